// Round 16
// baseline (93.625 us; speedup 1.0000x reference)
//
#include <hip/hip_runtime.h>
#include <hip/hip_bf16.h>

constexpr int B  = 256;
constexpr int E  = 16384;
constexpr int M  = 65536;
constexpr int H  = 128;
constexpr int NH = 4;
constexpr int HD = 32;
constexpr int LQ = 128;
constexpr int LK = 384;

// bf16 weight buffer offsets (elements)
constexpr int WQ_OFF  = 0;
constexpr int WK_OFF  = 16384;
constexpr int WV_OFF  = 32768;
constexpr int OPW_OFF = 49152;
constexpr int W1_OFF  = 65536;
constexpr int W2_OFF  = 98304;
constexpr int W_TOTAL = 131072;

typedef __attribute__((ext_vector_type(8))) short bf16x8;
typedef __attribute__((ext_vector_type(8))) unsigned short u16x8;
typedef __attribute__((ext_vector_type(4))) float f32x4;

__device__ __forceinline__ ushort f2bf(float x) {
  union { float f; unsigned u; } v; v.f = x;
  unsigned r = (v.u + 0x7FFFu + ((v.u >> 16) & 1u)) >> 16;
  return (ushort)r;
}
__device__ __forceinline__ unsigned pack2bf(float a, float b) {
  return (unsigned)f2bf(a) | ((unsigned)f2bf(b) << 16);
}

// ---------------- K1: starts + bf16 weights + bf16 edge_attr copy ----------------
__global__ __launch_bounds__(256) void k_starts_prep(
    const int* __restrict__ eb, const int* __restrict__ ieb,
    int* __restrict__ sq, int* __restrict__ sk,
    const float* __restrict__ in_proj_w, const float* __restrict__ opw,
    const float* __restrict__ w1, const float* __restrict__ w2,
    const float* __restrict__ edge_attr,
    ushort* __restrict__ Wb, ushort* __restrict__ Eb) {
  const int bx = blockIdx.x, t = threadIdx.x;
  if (bx == 0) {
    for (int i = t; i <= B; i += 256) {
      int lo = 0, hi = E;
      while (lo < hi) { int mid = (lo + hi) >> 1; if (eb[mid] < i) lo = mid + 1; else hi = mid; }
      sq[i] = lo;
      lo = 0; hi = M;
      while (lo < hi) { int mid = (lo + hi) >> 1; if (ieb[mid] < i) lo = mid + 1; else hi = mid; }
      sk[i] = lo;
    }
  } else if (bx <= 128) {
    int i = ((bx - 1) * 256 + t) * 4;
    if (i < W_TOTAL) {
      float4 v;
      if (i < OPW_OFF)      v = *(const float4*)(in_proj_w + i);
      else if (i < W1_OFF)  v = *(const float4*)(opw + (i - OPW_OFF));
      else if (i < W2_OFF)  v = *(const float4*)(w1 + (i - W1_OFF));
      else                  v = *(const float4*)(w2 + (i - W2_OFF));
      ushort4 o; o.x = f2bf(v.x); o.y = f2bf(v.y); o.z = f2bf(v.z); o.w = f2bf(v.w);
      *(ushort4*)(Wb + i) = o;
    }
  } else {
    int i = ((bx - 129) * 256 + t) * 4;   // E*H = 2M elems, 2048 blocks
    float4 v = *(const float4*)(edge_attr + i);
    ushort4 o; o.x = f2bf(v.x); o.y = f2bf(v.y); o.z = f2bf(v.z); o.w = f2bf(v.w);
    *(ushort4*)(Eb + i) = o;
  }
}

// ---------------- K2: fused QKV-projection + flash attention ----------------
// grid (B, NH), 256 threads = 4 waves, zero idle waves. KV-proj strided over
// 4 waves; flash: wave w owns q-tiles w, w+4, ... (Q projected per-tile into
// registers, P repack via shfl). LDS = K + V^T (52.4 KB) -> 3 blocks/CU.
__global__ __launch_bounds__(256, 2) void k_attn_fused(
    const ushort* __restrict__ Eb, const int* __restrict__ iel,
    const ushort* __restrict__ Wb, const float* __restrict__ in_proj_b,
    const int* __restrict__ sq, const int* __restrict__ sk,
    ushort* __restrict__ CtxB) {
  constexpr int KP = 36;
  constexpr int VP = 388;
  __shared__ ushort Kl[LK * KP];               // 27648 B
  __shared__ ushort VTl[HD * VP];              // 24832 B

  const int b = blockIdx.x, h = blockIdx.y;
  const int t = threadIdx.x;
  const int q0 = sq[b], lenq = sq[b + 1] - q0;
  const int k0 = sk[b], lenk = sk[b + 1] - k0;
  const int nq = lenq < LQ ? lenq : LQ;
  const int nk = lenk < LK ? lenk : LK;
  const int nkc = (nk + 63) & ~63;     // 64-granular padding
  const int nqt = (nq + 15) >> 4;
  const int nkt = nkc >> 4;

  const int w = t >> 6, lane = t & 63, g = lane >> 4, l15 = lane & 15;
  const int chb = h * HD;               // head channel base (32 ch)
  const ushort4 z4 = {0, 0, 0, 0};

  // ---- K,V projection: kt tiles strided over 4 waves ----
  {
    bf16x8 wkf[2][4], wvf[2][4];
#pragma unroll
    for (int ct = 0; ct < 2; ct++)
#pragma unroll
      for (int kc = 0; kc < 4; kc++) {
        wkf[ct][kc] = *(const bf16x8*)(Wb + WK_OFF + (size_t)(chb + ct * 16 + l15) * H + kc * 32 + g * 8);
        wvf[ct][kc] = *(const bf16x8*)(Wb + WV_OFF + (size_t)(chb + ct * 16 + l15) * H + kc * 32 + g * 8);
      }
    for (int kt = w; kt < nkt; kt += 4) {
      int slot = kt * 16 + l15;
      bool valid = slot < nk;
      int src = 0;
      if (valid) {
        int kj = k0 + slot;
        if (lenk > LK && slot == LK - 1) kj = k0 + lenk - 1;
        src = iel[kj];
      }
      bf16x8 rb[4];
#pragma unroll
      for (int kc = 0; kc < 4; kc++)
        rb[kc] = *(const bf16x8*)(Eb + (size_t)src * H + kc * 32 + g * 8);
      // K -> Kl row-major
#pragma unroll
      for (int ct = 0; ct < 2; ct++) {
        f32x4 acc = {0.f, 0.f, 0.f, 0.f};
#pragma unroll
        for (int kc = 0; kc < 4; kc++)
          acc = __builtin_amdgcn_mfma_f32_16x16x32_bf16(wkf[ct][kc], rb[kc], acc, 0, 0, 0);
        ushort4 v = z4;
        if (valid) {
          float4 bb = *(const float4*)(in_proj_b + H + chb + ct * 16 + 4 * g);
          v.x = f2bf(acc[0] + bb.x); v.y = f2bf(acc[1] + bb.y);
          v.z = f2bf(acc[2] + bb.z); v.w = f2bf(acc[3] + bb.w);
        }
        *(ushort4*)(Kl + (kt * 16 + l15) * KP + ct * 16 + 4 * g) = v;
      }
      // V -> VTl transposed (channel rows); pads zeroed
#pragma unroll
      for (int ct = 0; ct < 2; ct++) {
        f32x4 acc = {0.f, 0.f, 0.f, 0.f};
#pragma unroll
        for (int kc = 0; kc < 4; kc++)
          acc = __builtin_amdgcn_mfma_f32_16x16x32_bf16(wvf[ct][kc], rb[kc], acc, 0, 0, 0);
        if (valid) {
          float4 bb = *(const float4*)(in_proj_b + 2 * H + chb + ct * 16 + 4 * g);
          VTl[(ct * 16 + 4 * g + 0) * VP + kt * 16 + l15] = f2bf(acc[0] + bb.x);
          VTl[(ct * 16 + 4 * g + 1) * VP + kt * 16 + l15] = f2bf(acc[1] + bb.y);
          VTl[(ct * 16 + 4 * g + 2) * VP + kt * 16 + l15] = f2bf(acc[2] + bb.z);
          VTl[(ct * 16 + 4 * g + 3) * VP + kt * 16 + l15] = f2bf(acc[3] + bb.w);
        } else {
#pragma unroll
          for (int r = 0; r < 4; r++)
            VTl[(ct * 16 + 4 * g + r) * VP + kt * 16 + l15] = 0;
        }
      }
    }
  }

  // Q weight fragments (live through flash phase)
  bf16x8 wf[2][4];
#pragma unroll
  for (int ct = 0; ct < 2; ct++)
#pragma unroll
    for (int kc = 0; kc < 4; kc++)
      wf[ct][kc] = *(const bf16x8*)(Wb + WQ_OFF + (size_t)(chb + ct * 16 + l15) * H + kc * 32 + g * 8);
  __syncthreads();

  // ---- flash attention: wave w owns q-tiles w, w+4, ... ----
  const float scale = 0.17677669529663687f;  // 1/sqrt(32)
  for (int qt = w; qt < nqt; qt += 4) {
    // project Q tile qt into registers
    int slot = qt * 16 + l15;
    bool valid = slot < nq;
    int src = q0 + slot;
    if (lenq > LQ && slot == LQ - 1) src = q0 + lenq - 1;
    if (!valid) src = q0;
    bf16x8 rb[4];
#pragma unroll
    for (int kc = 0; kc < 4; kc++)
      rb[kc] = *(const bf16x8*)(Eb + (size_t)src * H + kc * 32 + g * 8);
    unsigned qw[2][2];
#pragma unroll
    for (int ct = 0; ct < 2; ct++) {
      f32x4 acc = {0.f, 0.f, 0.f, 0.f};
#pragma unroll
      for (int kc = 0; kc < 4; kc++)
        acc = __builtin_amdgcn_mfma_f32_16x16x32_bf16(wf[ct][kc], rb[kc], acc, 0, 0, 0);
      float4 bb = *(const float4*)(in_proj_b + chb + ct * 16 + 4 * g);
      qw[ct][0] = pack2bf(acc[0] + bb.x, acc[1] + bb.y);
      qw[ct][1] = pack2bf(acc[2] + bb.z, acc[3] + bb.w);
    }
    // repack D-layout -> B-frag: bq.dw[j] = channels (8g+2j, 8g+2j+1) of q=l15
    union { int i[4]; bf16x8 v; } bqd;
#pragma unroll
    for (int j = 0; j < 4; j++) {
      int sl = (2 * (g & 1) + (j >> 1)) * 16 + l15;
      int lo = __shfl((int)qw[0][j & 1], sl);
      int hi = __shfl((int)qw[1][j & 1], sl);
      bqd.i[j] = (g < 2) ? lo : hi;
    }
    bf16x8 bq = bqd.v;

    f32x4 o0 = {0.f, 0.f, 0.f, 0.f}, o1 = {0.f, 0.f, 0.f, 0.f};
    float m = -3.0e38f, s = 0.f;
    for (int kc = 0; kc < nk; kc += 64) {
      bf16x8 a0 = *(const bf16x8*)(Kl + (kc + l15) * KP + g * 8);
      bf16x8 a1 = *(const bf16x8*)(Kl + (kc + 16 + l15) * KP + g * 8);
      bf16x8 a2 = *(const bf16x8*)(Kl + (kc + 32 + l15) * KP + g * 8);
      bf16x8 a3 = *(const bf16x8*)(Kl + (kc + 48 + l15) * KP + g * 8);
      f32x4 z = {0.f, 0.f, 0.f, 0.f};
      f32x4 st0 = __builtin_amdgcn_mfma_f32_16x16x32_bf16(a0, bq, z, 0, 0, 0);
      f32x4 st1 = __builtin_amdgcn_mfma_f32_16x16x32_bf16(a1, bq, z, 0, 0, 0);
      f32x4 st2 = __builtin_amdgcn_mfma_f32_16x16x32_bf16(a2, bq, z, 0, 0, 0);
      f32x4 st3 = __builtin_amdgcn_mfma_f32_16x16x32_bf16(a3, bq, z, 0, 0, 0);
      float p[16];
#pragma unroll
      for (int r = 0; r < 4; r++) {
        p[r]      = (kc + 4 * g + r < nk)      ? st0[r] * scale : -1e30f;
        p[4 + r]  = (kc + 16 + 4 * g + r < nk) ? st1[r] * scale : -1e30f;
        p[8 + r]  = (kc + 32 + 4 * g + r < nk) ? st2[r] * scale : -1e30f;
        p[12 + r] = (kc + 48 + 4 * g + r < nk) ? st3[r] * scale : -1e30f;
      }
      float pm = p[0];
#pragma unroll
      for (int r = 1; r < 16; r++) pm = fmaxf(pm, p[r]);
      pm = fmaxf(pm, __shfl_xor(pm, 16));
      pm = fmaxf(pm, __shfl_xor(pm, 32));
      float mn = fmaxf(m, pm);
      float corr = __expf(m - mn);
      float rs = 0.f;
#pragma unroll
      for (int r = 0; r < 16; r++) { p[r] = __expf(p[r] - mn); rs += p[r]; }
      rs += __shfl_xor(rs, 16);
      rs += __shfl_xor(rs, 32);
      s = s * corr + rs;
      m = mn;
      // pack p -> 8 dwords, repack to B-frags via shfl (no LDS)
      unsigned pkw[4][2];
#pragma unroll
      for (int i = 0; i < 4; i++) {
        pkw[i][0] = pack2bf(p[4 * i + 0], p[4 * i + 1]);
        pkw[i][1] = pack2bf(p[4 * i + 2], p[4 * i + 3]);
      }
      union { int i[4]; bf16x8 v; } pb0, pb1;
#pragma unroll
      for (int j = 0; j < 4; j++) {
        int sl = (2 * (g & 1) + (j >> 1)) * 16 + l15;
        int a_ = __shfl((int)pkw[0][j & 1], sl);
        int b_ = __shfl((int)pkw[1][j & 1], sl);
        int c_ = __shfl((int)pkw[2][j & 1], sl);
        int d_ = __shfl((int)pkw[3][j & 1], sl);
        pb0.i[j] = (g < 2) ? a_ : b_;
        pb1.i[j] = (g < 2) ? c_ : d_;
      }
      bf16x8 av00 = *(const bf16x8*)(VTl + l15 * VP + kc + 8 * g);
      bf16x8 av01 = *(const bf16x8*)(VTl + l15 * VP + kc + 32 + 8 * g);
      bf16x8 av10 = *(const bf16x8*)(VTl + (16 + l15) * VP + kc + 8 * g);
      bf16x8 av11 = *(const bf16x8*)(VTl + (16 + l15) * VP + kc + 32 + 8 * g);
#pragma unroll
      for (int r = 0; r < 4; r++) { o0[r] *= corr; o1[r] *= corr; }
      o0 = __builtin_amdgcn_mfma_f32_16x16x32_bf16(av00, pb0.v, o0, 0, 0, 0);
      o0 = __builtin_amdgcn_mfma_f32_16x16x32_bf16(av01, pb1.v, o0, 0, 0, 0);
      o1 = __builtin_amdgcn_mfma_f32_16x16x32_bf16(av10, pb0.v, o1, 0, 0, 0);
      o1 = __builtin_amdgcn_mfma_f32_16x16x32_bf16(av11, pb1.v, o1, 0, 0, 0);
    }
    if (valid) {
      int qi = q0 + slot;
      if (lenq > LQ && slot == LQ - 1) qi = q0 + lenq - 1;
      ushort* outp = CtxB + (size_t)qi * H + chb;
      if (nk > 0) {
        float inv = 1.f / s;
        ushort4 v0, v1;
#pragma unroll
        for (int r = 0; r < 4; r++) { ((ushort*)&v0)[r] = f2bf(o0[r] * inv); ((ushort*)&v1)[r] = f2bf(o1[r] * inv); }
        *(ushort4*)(outp + 4 * g) = v0;
        *(ushort4*)(outp + 16 + 4 * g) = v1;
      } else {
        const float* bv = in_proj_b + 2 * H + chb;
        ushort4 v0, v1;
#pragma unroll
        for (int r = 0; r < 4; r++) { ((ushort*)&v0)[r] = f2bf(bv[4 * g + r]); ((ushort*)&v1)[r] = f2bf(bv[16 + 4 * g + r]); }
        *(ushort4*)(outp + 4 * g) = v0;
        *(ushort4*)(outp + 16 + 4 * g) = v1;
      }
    }
  }
}

// ---------------- K3: out-proj + residual + FFN (16-row blocks) ----------------
__global__ __launch_bounds__(256) void k_out_ffn_mfma(
    const ushort* __restrict__ CtxB, const float* __restrict__ edge_attr,
    const int* __restrict__ sq, const int* __restrict__ eb,
    const ushort* __restrict__ Wb, const float* __restrict__ opb,
    const float* __restrict__ b1, const float* __restrict__ b2,
    float* __restrict__ out) {
  constexpr int IP = 136;  // K=128 pitch
  constexpr int HP = 264;  // K=256 pitch
  __shared__ ushort attB[16 * IP];  // ctx staging, then att bf16
  __shared__ ushort h1L[16 * HP];   // h1 bf16
  const int t = threadIdx.x;
  const int row0 = blockIdx.x * 16;

  for (int idx = t; idx < 16 * 16; idx += 256) {
    int r = idx >> 4, c = idx & 15;
    int i = row0 + r;
    int bb = eb[i];
    int qq0 = sq[bb];
    int lenq = sq[bb + 1] - qq0;
    int src = i;
    if (lenq > LQ && (i - qq0) >= LQ - 1) src = qq0 + lenq - 1;
    *(u16x8*)(attB + r * IP + c * 8) = *(const u16x8*)(CtxB + (size_t)src * H + c * 8);
  }
  __syncthreads();

  const int w = t >> 6, lane = t & 63, g = lane >> 4, l15 = lane & 15;
  const int row = row0 + l15;
  bf16x8 ca[4];
#pragma unroll
  for (int kc = 0; kc < 4; kc++)
    ca[kc] = *(const bf16x8*)(attB + l15 * IP + kc * 32 + g * 8);
  __syncthreads();   // attB free for att writes

  // phase A: att = ctx @ opw^T + opb + edge_attr  (2 ct tiles per wave)
  float att[2][4];
#pragma unroll
  for (int ci = 0; ci < 2; ci++) {
    int ct = w * 2 + ci;
    f32x4 acc = {0.f, 0.f, 0.f, 0.f};
#pragma unroll
    for (int kc = 0; kc < 4; kc++) {
      bf16x8 bw = *(const bf16x8*)(Wb + OPW_OFF + (size_t)(ct * 16 + l15) * H + kc * 32 + g * 8);
      acc = __builtin_amdgcn_mfma_f32_16x16x32_bf16(bw, ca[kc], acc, 0, 0, 0);
    }
    int oc = ct * 16 + 4 * g;
    float4 bo = *(const float4*)(opb + oc);
    float4 ea = *(const float4*)(edge_attr + (size_t)row * H + oc);
    ushort4 v;
    att[ci][0] = acc[0] + bo.x + ea.x; v.x = f2bf(att[ci][0]);
    att[ci][1] = acc[1] + bo.y + ea.y; v.y = f2bf(att[ci][1]);
    att[ci][2] = acc[2] + bo.z + ea.z; v.z = f2bf(att[ci][2]);
    att[ci][3] = acc[3] + bo.w + ea.w; v.w = f2bf(att[ci][3]);
    *(ushort4*)(attB + l15 * IP + oc) = v;
  }
  __syncthreads();

  // phase B: h1 = relu(att @ w1^T + b1)  (4 ct tiles per wave)
  bf16x8 aa[4];
#pragma unroll
  for (int kc = 0; kc < 4; kc++)
    aa[kc] = *(const bf16x8*)(attB + l15 * IP + kc * 32 + g * 8);
#pragma unroll
  for (int ci = 0; ci < 4; ci++) {
    int ct = w * 4 + ci;
    f32x4 acc = {0.f, 0.f, 0.f, 0.f};
#pragma unroll
    for (int kc = 0; kc < 4; kc++) {
      bf16x8 bw = *(const bf16x8*)(Wb + W1_OFF + (size_t)(ct * 16 + l15) * H + kc * 32 + g * 8);
      acc = __builtin_amdgcn_mfma_f32_16x16x32_bf16(bw, aa[kc], acc, 0, 0, 0);
    }
    int oc = ct * 16 + 4 * g;
    float4 bb = *(const float4*)(b1 + oc);
    ushort4 v;
    v.x = f2bf(fmaxf(acc[0] + bb.x, 0.f)); v.y = f2bf(fmaxf(acc[1] + bb.y, 0.f));
    v.z = f2bf(fmaxf(acc[2] + bb.z, 0.f)); v.w = f2bf(fmaxf(acc[3] + bb.w, 0.f));
    *(ushort4*)(h1L + l15 * HP + oc) = v;
  }
  __syncthreads();

  // phase C: out = att + h1 @ w2^T + b2  (same 2 ct tiles as phase A)
  bf16x8 ha[8];
#pragma unroll
  for (int kc = 0; kc < 8; kc++)
    ha[kc] = *(const bf16x8*)(h1L + l15 * HP + kc * 32 + g * 8);
#pragma unroll
  for (int ci = 0; ci < 2; ci++) {
    int ct = w * 2 + ci;
    f32x4 acc = {0.f, 0.f, 0.f, 0.f};
#pragma unroll
    for (int kc = 0; kc < 8; kc++) {
      bf16x8 bw = *(const bf16x8*)(Wb + W2_OFF + (size_t)(ct * 16 + l15) * 2 * H + kc * 32 + g * 8);
      acc = __builtin_amdgcn_mfma_f32_16x16x32_bf16(bw, ha[kc], acc, 0, 0, 0);
    }
    int oc = ct * 16 + 4 * g;
    float4 bb = *(const float4*)(b2 + oc);
    float4 o;
    o.x = att[ci][0] + acc[0] + bb.x;
    o.y = att[ci][1] + acc[1] + bb.y;
    o.z = att[ci][2] + acc[2] + bb.z;
    o.w = att[ci][3] + acc[3] + bb.w;
    *(float4*)(out + (size_t)row * H + oc) = o;
  }
}

extern "C" void kernel_launch(void* const* d_in, const int* in_sizes, int n_in,
                              void* d_out, int out_size, void* d_ws, size_t ws_size,
                              hipStream_t stream) {
  const float* edge_attr = (const float*)d_in[1];
  const int*   iel       = (const int*)d_in[2];
  const int*   ieb       = (const int*)d_in[3];
  const int*   eb        = (const int*)d_in[4];
  const float* in_proj_w = (const float*)d_in[5];
  const float* in_proj_b = (const float*)d_in[6];
  const float* opw       = (const float*)d_in[7];
  const float* opb       = (const float*)d_in[8];
  const float* w1        = (const float*)d_in[9];
  const float* b1        = (const float*)d_in[10];
  const float* w2        = (const float*)d_in[11];
  const float* b2        = (const float*)d_in[12];
  float* out = (float*)d_out;

  char* ws = (char*)d_ws;
  int* sq = (int*)ws;
  int* sk = (int*)(ws + 2048);
  ushort* CtxB = (ushort*)(ws + 4096);            // E*H bf16
  ushort* Wb   = CtxB + (size_t)E * H;            // 131072 bf16 weights
  ushort* Eb   = Wb + W_TOTAL;                    // E*H bf16 edge_attr

  k_starts_prep<<<dim3(2177), dim3(256), 0, stream>>>(eb, ieb, sq, sk, in_proj_w, opw, w1, w2, edge_attr, Wb, Eb);
  k_attn_fused<<<dim3(B, NH), dim3(256), 0, stream>>>(Eb, iel, Wb, in_proj_b, sq, sk, CtxB);
  k_out_ffn_mfma<<<dim3(E / 16), dim3(256), 0, stream>>>(CtxB, edge_attr, sq, eb, Wb, opb, b1, b2, out);
}

// Round 20
// 90.783 us; speedup vs baseline: 1.0313x; 1.0313x over previous
//
#include <hip/hip_runtime.h>
#include <hip/hip_bf16.h>

constexpr int B  = 256;
constexpr int E  = 16384;
constexpr int M  = 65536;
constexpr int H  = 128;
constexpr int NH = 4;
constexpr int HD = 32;
constexpr int LQ = 128;
constexpr int LK = 384;

// bf16 weight buffer offsets (elements)
constexpr int WQ_OFF  = 0;
constexpr int WK_OFF  = 16384;
constexpr int WV_OFF  = 32768;
constexpr int OPW_OFF = 49152;
constexpr int W1_OFF  = 65536;
constexpr int W2_OFF  = 98304;
constexpr int W_TOTAL = 131072;

typedef __attribute__((ext_vector_type(8))) short bf16x8;
typedef __attribute__((ext_vector_type(8))) unsigned short u16x8;
typedef __attribute__((ext_vector_type(4))) float f32x4;

__device__ __forceinline__ ushort f2bf(float x) {
  union { float f; unsigned u; } v; v.f = x;
  unsigned r = (v.u + 0x7FFFu + ((v.u >> 16) & 1u)) >> 16;
  return (ushort)r;
}
__device__ __forceinline__ unsigned pack2bf(float a, float b) {
  return (unsigned)f2bf(a) | ((unsigned)f2bf(b) << 16);
}

// ---------------- K1: starts + bf16 weights + bf16 edge_attr copy ----------------
__global__ __launch_bounds__(256) void k_starts_prep(
    const int* __restrict__ eb, const int* __restrict__ ieb,
    int* __restrict__ sq, int* __restrict__ sk,
    const float* __restrict__ in_proj_w, const float* __restrict__ opw,
    const float* __restrict__ w1, const float* __restrict__ w2,
    const float* __restrict__ edge_attr,
    ushort* __restrict__ Wb, ushort* __restrict__ Eb) {
  const int bx = blockIdx.x, t = threadIdx.x;
  if (bx == 0) {
    for (int i = t; i <= B; i += 256) {
      int lo = 0, hi = E;
      while (lo < hi) { int mid = (lo + hi) >> 1; if (eb[mid] < i) lo = mid + 1; else hi = mid; }
      sq[i] = lo;
      lo = 0; hi = M;
      while (lo < hi) { int mid = (lo + hi) >> 1; if (ieb[mid] < i) lo = mid + 1; else hi = mid; }
      sk[i] = lo;
    }
  } else if (bx <= 128) {
    int i = ((bx - 1) * 256 + t) * 4;
    if (i < W_TOTAL) {
      float4 v;
      if (i < OPW_OFF)      v = *(const float4*)(in_proj_w + i);
      else if (i < W1_OFF)  v = *(const float4*)(opw + (i - OPW_OFF));
      else if (i < W2_OFF)  v = *(const float4*)(w1 + (i - W1_OFF));
      else                  v = *(const float4*)(w2 + (i - W2_OFF));
      ushort4 o; o.x = f2bf(v.x); o.y = f2bf(v.y); o.z = f2bf(v.z); o.w = f2bf(v.w);
      *(ushort4*)(Wb + i) = o;
    }
  } else {
    int i = ((bx - 129) * 256 + t) * 4;   // E*H = 2M elems, 2048 blocks
    float4 v = *(const float4*)(edge_attr + i);
    ushort4 o; o.x = f2bf(v.x); o.y = f2bf(v.y); o.z = f2bf(v.z); o.w = f2bf(v.w);
    *(ushort4*)(Eb + i) = o;
  }
}

// ---------------- K2: dense Q/K/V projection of all E edges ----------------
// grid E/32, 256 threads = 4 waves. Wave handles row-tile (w&1), ct-half
// (w>>1). Per pass p in {Q,K,V}: 4 ct tiles x 4 MFMA, direct ushort4 stores.
__global__ __launch_bounds__(256) void k_proj_all(
    const ushort* __restrict__ Eb, const ushort* __restrict__ Wb,
    const float* __restrict__ in_proj_b,
    ushort* __restrict__ Qall, ushort* __restrict__ Kall, ushort* __restrict__ Vall) {
  constexpr int IP = 136;
  __shared__ ushort inL[32 * IP];
  const int t = threadIdx.x;
  const int row0 = blockIdx.x * 32;
  for (int idx = t; idx < 32 * 16; idx += 256) {
    int r = idx >> 4, c = idx & 15;
    *(u16x8*)(inL + r * IP + c * 8) = *(const u16x8*)(Eb + (size_t)(row0 + r) * H + c * 8);
  }
  __syncthreads();
  const int w = t >> 6, lane = t & 63, g = lane >> 4, l15 = lane & 15;
  const int wr = (w & 1) * 16, ch = w >> 1;
  bf16x8 a[4];
#pragma unroll
  for (int kc = 0; kc < 4; kc++)
    a[kc] = *(const bf16x8*)(inL + (wr + l15) * IP + kc * 32 + g * 8);
  const int row = row0 + wr + l15;
#pragma unroll
  for (int p = 0; p < 3; p++) {
    const int woff = WQ_OFF + p * 16384;
    const float* bias = in_proj_b + p * H;
    ushort* dst = (p == 0) ? Qall : (p == 1) ? Kall : Vall;
#pragma unroll
    for (int ci = 0; ci < 4; ci++) {
      int ct = ch * 4 + ci;
      f32x4 acc = {0.f, 0.f, 0.f, 0.f};
#pragma unroll
      for (int kc = 0; kc < 4; kc++) {
        bf16x8 bw = *(const bf16x8*)(Wb + woff + (size_t)(ct * 16 + l15) * H + kc * 32 + g * 8);
        acc = __builtin_amdgcn_mfma_f32_16x16x32_bf16(bw, a[kc], acc, 0, 0, 0);
      }
      int oc = ct * 16 + 4 * g;
      float4 bb = *(const float4*)(bias + oc);
      ushort4 v;
      v.x = f2bf(acc[0] + bb.x); v.y = f2bf(acc[1] + bb.y);
      v.z = f2bf(acc[2] + bb.z); v.w = f2bf(acc[3] + bb.w);
      *(ushort4*)(dst + (size_t)row * H + oc) = v;
    }
  }
}

// ---------------- K3: flash attention over projected head slices ----------------
// grid (B, NH), 256 threads = 4 waves. Stage K/V head slices (gather 64B
// slices of projected rows) into LDS; Q read directly from global as B-frag.
__global__ __launch_bounds__(256, 2) void k_attn_g(
    const ushort* __restrict__ Qall, const ushort* __restrict__ Kall,
    const ushort* __restrict__ Vall, const int* __restrict__ iel,
    const float* __restrict__ in_proj_b,
    const int* __restrict__ sq, const int* __restrict__ sk,
    ushort* __restrict__ CtxB) {
  constexpr int KP = 36;
  constexpr int VP = 388;
  __shared__ ushort Kl[LK * KP];               // 27648 B
  __shared__ ushort VTl[HD * VP];              // 24832 B

  const int b = blockIdx.x, h = blockIdx.y;
  const int t = threadIdx.x;
  const int q0 = sq[b], lenq = sq[b + 1] - q0;
  const int k0 = sk[b], lenk = sk[b + 1] - k0;
  const int nq = lenq < LQ ? lenq : LQ;
  const int nk = lenk < LK ? lenk : LK;
  const int nkc = (nk + 63) & ~63;     // 64-granular padding
  const int nqt = (nq + 15) >> 4;

  const int w = t >> 6, lane = t & 63, g = lane >> 4, l15 = lane & 15;
  const int chb = h * HD;               // head channel base (32 ch)
  const u16x8 z8 = {0, 0, 0, 0, 0, 0, 0, 0};

  // ---- stage K head-slices (row-major) ----
  for (int idx = t; idx < nk * 4; idx += 256) {
    int row = idx >> 2, c = idx & 3;
    int kj = k0 + row;
    if (lenk > LK && row == LK - 1) kj = k0 + lenk - 1;
    int src = iel[kj];
    *(u16x8*)(Kl + row * KP + c * 8) = *(const u16x8*)(Kall + (size_t)src * H + chb + c * 8);
  }
  for (int idx = t; idx < (nkc - nk) * 4; idx += 256) {
    int row = nk + (idx >> 2), c = idx & 3;
    *(u16x8*)(Kl + row * KP + c * 8) = z8;
  }
  // ---- stage V head-slices transposed ----
  for (int idx = t; idx < nk * 4; idx += 256) {
    int row = idx >> 2, c = idx & 3;
    int kj = k0 + row;
    if (lenk > LK && row == LK - 1) kj = k0 + lenk - 1;
    int src = iel[kj];
    u16x8 v = *(const u16x8*)(Vall + (size_t)src * H + chb + c * 8);
#pragma unroll
    for (int j = 0; j < 8; j++) VTl[(c * 8 + j) * VP + row] = v[j];
  }
  for (int idx = t; idx < ((nkc - nk) << 5); idx += 256) {
    int d = idx & 31, k = nk + (idx >> 5);
    VTl[d * VP + k] = 0;
  }
  __syncthreads();

  // ---- flash: wave w owns q-tiles w, w+4, ... ----
  const float scale = 0.17677669529663687f;  // 1/sqrt(32)
  for (int qt = w; qt < nqt; qt += 4) {
    int slot = qt * 16 + l15;
    bool valid = slot < nq;
    int src = q0 + slot;
    if (lenq > LQ && slot == LQ - 1) src = q0 + lenq - 1;
    if (!valid) src = q0;
    // Q B-frag directly from global: n = q (l15), k = channels 8g..8g+7
    bf16x8 bq = *(const bf16x8*)(Qall + (size_t)src * H + chb + g * 8);

    f32x4 o0 = {0.f, 0.f, 0.f, 0.f}, o1 = {0.f, 0.f, 0.f, 0.f};
    float m = -3.0e38f, s = 0.f;
    for (int kc = 0; kc < nk; kc += 64) {
      bf16x8 a0 = *(const bf16x8*)(Kl + (kc + l15) * KP + g * 8);
      bf16x8 a1 = *(const bf16x8*)(Kl + (kc + 16 + l15) * KP + g * 8);
      bf16x8 a2 = *(const bf16x8*)(Kl + (kc + 32 + l15) * KP + g * 8);
      bf16x8 a3 = *(const bf16x8*)(Kl + (kc + 48 + l15) * KP + g * 8);
      f32x4 z = {0.f, 0.f, 0.f, 0.f};
      f32x4 st0 = __builtin_amdgcn_mfma_f32_16x16x32_bf16(a0, bq, z, 0, 0, 0);
      f32x4 st1 = __builtin_amdgcn_mfma_f32_16x16x32_bf16(a1, bq, z, 0, 0, 0);
      f32x4 st2 = __builtin_amdgcn_mfma_f32_16x16x32_bf16(a2, bq, z, 0, 0, 0);
      f32x4 st3 = __builtin_amdgcn_mfma_f32_16x16x32_bf16(a3, bq, z, 0, 0, 0);
      float p[16];
#pragma unroll
      for (int r = 0; r < 4; r++) {
        p[r]      = (kc + 4 * g + r < nk)      ? st0[r] * scale : -1e30f;
        p[4 + r]  = (kc + 16 + 4 * g + r < nk) ? st1[r] * scale : -1e30f;
        p[8 + r]  = (kc + 32 + 4 * g + r < nk) ? st2[r] * scale : -1e30f;
        p[12 + r] = (kc + 48 + 4 * g + r < nk) ? st3[r] * scale : -1e30f;
      }
      float pm = p[0];
#pragma unroll
      for (int r = 1; r < 16; r++) pm = fmaxf(pm, p[r]);
      pm = fmaxf(pm, __shfl_xor(pm, 16));
      pm = fmaxf(pm, __shfl_xor(pm, 32));
      float mn = fmaxf(m, pm);
      float corr = __expf(m - mn);
      float rs = 0.f;
#pragma unroll
      for (int r = 0; r < 16; r++) { p[r] = __expf(p[r] - mn); rs += p[r]; }
      rs += __shfl_xor(rs, 16);
      rs += __shfl_xor(rs, 32);
      s = s * corr + rs;
      m = mn;
      // pack p -> 8 dwords, repack to B-frags via shfl (no LDS)
      unsigned pkw[4][2];
#pragma unroll
      for (int i = 0; i < 4; i++) {
        pkw[i][0] = pack2bf(p[4 * i + 0], p[4 * i + 1]);
        pkw[i][1] = pack2bf(p[4 * i + 2], p[4 * i + 3]);
      }
      union { int i[4]; bf16x8 v; } pb0, pb1;
#pragma unroll
      for (int j = 0; j < 4; j++) {
        int sl = (2 * (g & 1) + (j >> 1)) * 16 + l15;
        int a_ = __shfl((int)pkw[0][j & 1], sl);
        int b_ = __shfl((int)pkw[1][j & 1], sl);
        int c_ = __shfl((int)pkw[2][j & 1], sl);
        int d_ = __shfl((int)pkw[3][j & 1], sl);
        pb0.i[j] = (g < 2) ? a_ : b_;
        pb1.i[j] = (g < 2) ? c_ : d_;
      }
      bf16x8 av00 = *(const bf16x8*)(VTl + l15 * VP + kc + 8 * g);
      bf16x8 av01 = *(const bf16x8*)(VTl + l15 * VP + kc + 32 + 8 * g);
      bf16x8 av10 = *(const bf16x8*)(VTl + (16 + l15) * VP + kc + 8 * g);
      bf16x8 av11 = *(const bf16x8*)(VTl + (16 + l15) * VP + kc + 32 + 8 * g);
#pragma unroll
      for (int r = 0; r < 4; r++) { o0[r] *= corr; o1[r] *= corr; }
      o0 = __builtin_amdgcn_mfma_f32_16x16x32_bf16(av00, pb0.v, o0, 0, 0, 0);
      o0 = __builtin_amdgcn_mfma_f32_16x16x32_bf16(av01, pb1.v, o0, 0, 0, 0);
      o1 = __builtin_amdgcn_mfma_f32_16x16x32_bf16(av10, pb0.v, o1, 0, 0, 0);
      o1 = __builtin_amdgcn_mfma_f32_16x16x32_bf16(av11, pb1.v, o1, 0, 0, 0);
    }
    if (valid) {
      int qi = q0 + slot;
      if (lenq > LQ && slot == LQ - 1) qi = q0 + lenq - 1;
      ushort* outp = CtxB + (size_t)qi * H + chb;
      if (nk > 0) {
        float inv = 1.f / s;
        ushort4 v0, v1;
#pragma unroll
        for (int r = 0; r < 4; r++) { ((ushort*)&v0)[r] = f2bf(o0[r] * inv); ((ushort*)&v1)[r] = f2bf(o1[r] * inv); }
        *(ushort4*)(outp + 4 * g) = v0;
        *(ushort4*)(outp + 16 + 4 * g) = v1;
      } else {
        const float* bv = in_proj_b + 2 * H + chb;
        ushort4 v0, v1;
#pragma unroll
        for (int r = 0; r < 4; r++) { ((ushort*)&v0)[r] = f2bf(bv[4 * g + r]); ((ushort*)&v1)[r] = f2bf(bv[16 + 4 * g + r]); }
        *(ushort4*)(outp + 4 * g) = v0;
        *(ushort4*)(outp + 16 + 4 * g) = v1;
      }
    }
  }
}

// ---------------- K4: out-proj + residual + FFN (16-row blocks) ----------------
__global__ __launch_bounds__(256) void k_out_ffn_mfma(
    const ushort* __restrict__ CtxB, const float* __restrict__ edge_attr,
    const int* __restrict__ sq, const int* __restrict__ eb,
    const ushort* __restrict__ Wb, const float* __restrict__ opb,
    const float* __restrict__ b1, const float* __restrict__ b2,
    float* __restrict__ out) {
  constexpr int IP = 136;  // K=128 pitch
  constexpr int HP = 264;  // K=256 pitch
  __shared__ ushort attB[16 * IP];  // ctx staging, then att bf16
  __shared__ ushort h1L[16 * HP];   // h1 bf16
  const int t = threadIdx.x;
  const int row0 = blockIdx.x * 16;

  for (int idx = t; idx < 16 * 16; idx += 256) {
    int r = idx >> 4, c = idx & 15;
    int i = row0 + r;
    int bb = eb[i];
    int qq0 = sq[bb];
    int lenq = sq[bb + 1] - qq0;
    int src = i;
    if (lenq > LQ && (i - qq0) >= LQ - 1) src = qq0 + lenq - 1;
    *(u16x8*)(attB + r * IP + c * 8) = *(const u16x8*)(CtxB + (size_t)src * H + c * 8);
  }
  __syncthreads();

  const int w = t >> 6, lane = t & 63, g = lane >> 4, l15 = lane & 15;
  const int row = row0 + l15;
  bf16x8 ca[4];
#pragma unroll
  for (int kc = 0; kc < 4; kc++)
    ca[kc] = *(const bf16x8*)(attB + l15 * IP + kc * 32 + g * 8);
  __syncthreads();   // attB free for att writes

  // phase A: att = ctx @ opw^T + opb + edge_attr  (2 ct tiles per wave)
  float att[2][4];
#pragma unroll
  for (int ci = 0; ci < 2; ci++) {
    int ct = w * 2 + ci;
    f32x4 acc = {0.f, 0.f, 0.f, 0.f};
#pragma unroll
    for (int kc = 0; kc < 4; kc++) {
      bf16x8 bw = *(const bf16x8*)(Wb + OPW_OFF + (size_t)(ct * 16 + l15) * H + kc * 32 + g * 8);
      acc = __builtin_amdgcn_mfma_f32_16x16x32_bf16(bw, ca[kc], acc, 0, 0, 0);
    }
    int oc = ct * 16 + 4 * g;
    float4 bo = *(const float4*)(opb + oc);
    float4 ea = *(const float4*)(edge_attr + (size_t)row * H + oc);
    ushort4 v;
    att[ci][0] = acc[0] + bo.x + ea.x; v.x = f2bf(att[ci][0]);
    att[ci][1] = acc[1] + bo.y + ea.y; v.y = f2bf(att[ci][1]);
    att[ci][2] = acc[2] + bo.z + ea.z; v.z = f2bf(att[ci][2]);
    att[ci][3] = acc[3] + bo.w + ea.w; v.w = f2bf(att[ci][3]);
    *(ushort4*)(attB + l15 * IP + oc) = v;
  }
  __syncthreads();

  // phase B: h1 = relu(att @ w1^T + b1)  (4 ct tiles per wave)
  bf16x8 aa[4];
#pragma unroll
  for (int kc = 0; kc < 4; kc++)
    aa[kc] = *(const bf16x8*)(attB + l15 * IP + kc * 32 + g * 8);
#pragma unroll
  for (int ci = 0; ci < 4; ci++) {
    int ct = w * 4 + ci;
    f32x4 acc = {0.f, 0.f, 0.f, 0.f};
#pragma unroll
    for (int kc = 0; kc < 4; kc++) {
      bf16x8 bw = *(const bf16x8*)(Wb + W1_OFF + (size_t)(ct * 16 + l15) * H + kc * 32 + g * 8);
      acc = __builtin_amdgcn_mfma_f32_16x16x32_bf16(bw, aa[kc], acc, 0, 0, 0);
    }
    int oc = ct * 16 + 4 * g;
    float4 bb = *(const float4*)(b1 + oc);
    ushort4 v;
    v.x = f2bf(fmaxf(acc[0] + bb.x, 0.f)); v.y = f2bf(fmaxf(acc[1] + bb.y, 0.f));
    v.z = f2bf(fmaxf(acc[2] + bb.z, 0.f)); v.w = f2bf(fmaxf(acc[3] + bb.w, 0.f));
    *(ushort4*)(h1L + l15 * HP + oc) = v;
  }
  __syncthreads();

  // phase C: out = att + h1 @ w2^T + b2  (same 2 ct tiles as phase A)
  bf16x8 ha[8];
#pragma unroll
  for (int kc = 0; kc < 8; kc++)
    ha[kc] = *(const bf16x8*)(h1L + l15 * HP + kc * 32 + g * 8);
#pragma unroll
  for (int ci = 0; ci < 2; ci++) {
    int ct = w * 2 + ci;
    f32x4 acc = {0.f, 0.f, 0.f, 0.f};
#pragma unroll
    for (int kc = 0; kc < 8; kc++) {
      bf16x8 bw = *(const bf16x8*)(Wb + W2_OFF + (size_t)(ct * 16 + l15) * 2 * H + kc * 32 + g * 8);
      acc = __builtin_amdgcn_mfma_f32_16x16x32_bf16(bw, ha[kc], acc, 0, 0, 0);
    }
    int oc = ct * 16 + 4 * g;
    float4 bb = *(const float4*)(b2 + oc);
    float4 o;
    o.x = att[ci][0] + acc[0] + bb.x;
    o.y = att[ci][1] + acc[1] + bb.y;
    o.z = att[ci][2] + acc[2] + bb.z;
    o.w = att[ci][3] + acc[3] + bb.w;
    *(float4*)(out + (size_t)row * H + oc) = o;
  }
}

extern "C" void kernel_launch(void* const* d_in, const int* in_sizes, int n_in,
                              void* d_out, int out_size, void* d_ws, size_t ws_size,
                              hipStream_t stream) {
  const float* edge_attr = (const float*)d_in[1];
  const int*   iel       = (const int*)d_in[2];
  const int*   ieb       = (const int*)d_in[3];
  const int*   eb        = (const int*)d_in[4];
  const float* in_proj_w = (const float*)d_in[5];
  const float* in_proj_b = (const float*)d_in[6];
  const float* opw       = (const float*)d_in[7];
  const float* opb       = (const float*)d_in[8];
  const float* w1        = (const float*)d_in[9];
  const float* b1        = (const float*)d_in[10];
  const float* w2        = (const float*)d_in[11];
  const float* b2        = (const float*)d_in[12];
  float* out = (float*)d_out;

  char* ws = (char*)d_ws;
  int* sq = (int*)ws;
  int* sk = (int*)(ws + 2048);
  ushort* CtxB = (ushort*)(ws + 4096);            // E*H bf16
  ushort* Wb   = CtxB + (size_t)E * H;            // 131072 bf16 weights
  ushort* Eb   = Wb + W_TOTAL;                    // E*H bf16 edge_attr
  ushort* Qall = Eb + (size_t)E * H;              // E*H bf16
  ushort* Kall = Qall + (size_t)E * H;            // E*H bf16
  ushort* Vall = Kall + (size_t)E * H;            // E*H bf16

  k_starts_prep<<<dim3(2177), dim3(256), 0, stream>>>(eb, ieb, sq, sk, in_proj_w, opw, w1, w2, edge_attr, Wb, Eb);
  k_proj_all<<<dim3(E / 32), dim3(256), 0, stream>>>(Eb, Wb, in_proj_b, Qall, Kall, Vall);
  k_attn_g<<<dim3(B, NH), dim3(256), 0, stream>>>(Qall, Kall, Vall, iel, in_proj_b, sq, sk, CtxB);
  k_out_ffn_mfma<<<dim3(E / 16), dim3(256), 0, stream>>>(CtxB, edge_attr, sq, eb, Wb, opb, b1, b2, out);
}

// Round 21
// 83.301 us; speedup vs baseline: 1.1239x; 1.0898x over previous
//
#include <hip/hip_runtime.h>
#include <hip/hip_bf16.h>

constexpr int B  = 256;
constexpr int E  = 16384;
constexpr int M  = 65536;
constexpr int H  = 128;
constexpr int NH = 4;
constexpr int HD = 32;
constexpr int LQ = 128;
constexpr int LK = 384;

// bf16 weight buffer offsets (elements)
constexpr int WQ_OFF  = 0;
constexpr int WK_OFF  = 16384;
constexpr int WV_OFF  = 32768;
constexpr int OPW_OFF = 49152;
constexpr int W1_OFF  = 65536;
constexpr int W2_OFF  = 98304;
constexpr int W_TOTAL = 131072;

typedef __attribute__((ext_vector_type(8))) short bf16x8;
typedef __attribute__((ext_vector_type(8))) unsigned short u16x8;
typedef __attribute__((ext_vector_type(4))) float f32x4;

__device__ __forceinline__ ushort f2bf(float x) {
  union { float f; unsigned u; } v; v.f = x;
  unsigned r = (v.u + 0x7FFFu + ((v.u >> 16) & 1u)) >> 16;
  return (ushort)r;
}
__device__ __forceinline__ unsigned pack2bf(float a, float b) {
  return (unsigned)f2bf(a) | ((unsigned)f2bf(b) << 16);
}

// ---------------- K1: segment starts + bf16 weight prep ----------------
__global__ __launch_bounds__(256) void k_starts_prep(
    const int* __restrict__ eb, const int* __restrict__ ieb,
    int* __restrict__ sq, int* __restrict__ sk,
    const float* __restrict__ in_proj_w, const float* __restrict__ opw,
    const float* __restrict__ w1, const float* __restrict__ w2,
    ushort* __restrict__ Wb) {
  const int bx = blockIdx.x, t = threadIdx.x;
  if (bx == 0) {
    for (int i = t; i <= B; i += 256) {
      int lo = 0, hi = E;
      while (lo < hi) { int mid = (lo + hi) >> 1; if (eb[mid] < i) lo = mid + 1; else hi = mid; }
      sq[i] = lo;
      lo = 0; hi = M;
      while (lo < hi) { int mid = (lo + hi) >> 1; if (ieb[mid] < i) lo = mid + 1; else hi = mid; }
      sk[i] = lo;
    }
  } else {
    int i = ((bx - 1) * 256 + t) * 4;
    if (i < W_TOTAL) {
      float4 v;
      if (i < OPW_OFF)      v = *(const float4*)(in_proj_w + i);
      else if (i < W1_OFF)  v = *(const float4*)(opw + (i - OPW_OFF));
      else if (i < W2_OFF)  v = *(const float4*)(w1 + (i - W1_OFF));
      else                  v = *(const float4*)(w2 + (i - W2_OFF));
      ushort4 o; o.x = f2bf(v.x); o.y = f2bf(v.y); o.z = f2bf(v.z); o.w = f2bf(v.w);
      *(ushort4*)(Wb + i) = o;
    }
  }
}

// ---------------- K2: dense Q/K/V projection of all E edges (fp32 in) ----------------
// grid E/32, 256 threads = 4 waves. Converts edge_attr fp32->bf16 during
// staging (same f2bf values as before). Direct ushort4 stores.
__global__ __launch_bounds__(256) void k_proj_all(
    const float* __restrict__ edge_attr, const ushort* __restrict__ Wb,
    const float* __restrict__ in_proj_b,
    ushort* __restrict__ Qall, ushort* __restrict__ Kall, ushort* __restrict__ Vall) {
  constexpr int IP = 136;
  __shared__ ushort inL[32 * IP];
  const int t = threadIdx.x;
  const int row0 = blockIdx.x * 32;
  for (int idx = t; idx < 32 * 32; idx += 256) {
    int r = idx >> 5, c = idx & 31;
    float4 v = ((const float4*)(edge_attr + (size_t)(row0 + r) * H))[c];
    ushort4 o; o.x = f2bf(v.x); o.y = f2bf(v.y); o.z = f2bf(v.z); o.w = f2bf(v.w);
    *(ushort4*)(inL + r * IP + c * 4) = o;
  }
  __syncthreads();
  const int w = t >> 6, lane = t & 63, g = lane >> 4, l15 = lane & 15;
  const int wr = (w & 1) * 16, ch = w >> 1;
  bf16x8 a[4];
#pragma unroll
  for (int kc = 0; kc < 4; kc++)
    a[kc] = *(const bf16x8*)(inL + (wr + l15) * IP + kc * 32 + g * 8);
  const int row = row0 + wr + l15;
#pragma unroll
  for (int p = 0; p < 3; p++) {
    const int woff = WQ_OFF + p * 16384;
    const float* bias = in_proj_b + p * H;
    ushort* dst = (p == 0) ? Qall : (p == 1) ? Kall : Vall;
#pragma unroll
    for (int ci = 0; ci < 4; ci++) {
      int ct = ch * 4 + ci;
      f32x4 acc = {0.f, 0.f, 0.f, 0.f};
#pragma unroll
      for (int kc = 0; kc < 4; kc++) {
        bf16x8 bw = *(const bf16x8*)(Wb + woff + (size_t)(ct * 16 + l15) * H + kc * 32 + g * 8);
        acc = __builtin_amdgcn_mfma_f32_16x16x32_bf16(bw, a[kc], acc, 0, 0, 0);
      }
      int oc = ct * 16 + 4 * g;
      float4 bb = *(const float4*)(bias + oc);
      ushort4 v;
      v.x = f2bf(acc[0] + bb.x); v.y = f2bf(acc[1] + bb.y);
      v.z = f2bf(acc[2] + bb.z); v.w = f2bf(acc[3] + bb.w);
      *(ushort4*)(dst + (size_t)row * H + oc) = v;
    }
  }
}

// ---------------- K3: flash attention; K from global, V^T in LDS ----------------
// grid (B, NH), 256 threads = 4 waves. K A-frags are per-lane 16B loads from
// L2-resident Kall via the srcL index table; invalid rows masked at p[] (as
// always). LDS = V^T (24.8KB) + srcL (1.5KB) -> high occupancy.
__global__ __launch_bounds__(256, 4) void k_attn_g(
    const ushort* __restrict__ Qall, const ushort* __restrict__ Kall,
    const ushort* __restrict__ Vall, const int* __restrict__ iel,
    const float* __restrict__ in_proj_b,
    const int* __restrict__ sq, const int* __restrict__ sk,
    ushort* __restrict__ CtxB) {
  constexpr int VP = 388;
  __shared__ ushort VTl[HD * VP];              // 24832 B
  __shared__ int srcL[LK];                     //  1536 B

  const int b = blockIdx.x, h = blockIdx.y;
  const int t = threadIdx.x;
  const int q0 = sq[b], lenq = sq[b + 1] - q0;
  const int k0 = sk[b], lenk = sk[b + 1] - k0;
  const int nq = lenq < LQ ? lenq : LQ;
  const int nk = lenk < LK ? lenk : LK;
  const int nkc = (nk + 63) & ~63;     // 64-granular padding
  const int nqt = (nq + 15) >> 4;

  const int w = t >> 6, lane = t & 63, g = lane >> 4, l15 = lane & 15;
  const int chb = h * HD;               // head channel base (32 ch)

  // ---- resolve gather indices (with LK clip) ----
  for (int idx = t; idx < nk; idx += 256) {
    int kj = k0 + idx;
    if (lenk > LK && idx == LK - 1) kj = k0 + lenk - 1;
    srcL[idx] = iel[kj];
  }
  // ---- stage V head-slices transposed ----
  for (int idx = t; idx < nk * 4; idx += 256) {
    int row = idx >> 2, c = idx & 3;
    int kj = k0 + row;
    if (lenk > LK && row == LK - 1) kj = k0 + lenk - 1;
    int src = iel[kj];
    u16x8 v = *(const u16x8*)(Vall + (size_t)src * H + chb + c * 8);
#pragma unroll
    for (int j = 0; j < 8; j++) VTl[(c * 8 + j) * VP + row] = v[j];
  }
  for (int idx = t; idx < ((nkc - nk) << 5); idx += 256) {
    int d = idx & 31, k = nk + (idx >> 5);
    VTl[d * VP + k] = 0;
  }
  __syncthreads();

  // ---- flash: wave w owns q-tiles w, w+4, ... ----
  const float scale = 0.17677669529663687f;  // 1/sqrt(32)
  for (int qt = w; qt < nqt; qt += 4) {
    int slot = qt * 16 + l15;
    bool valid = slot < nq;
    int src = q0 + slot;
    if (lenq > LQ && slot == LQ - 1) src = q0 + lenq - 1;
    if (!valid) src = q0;
    // Q B-frag directly from global: n = q (l15), k = channels 8g..8g+7
    bf16x8 bq = *(const bf16x8*)(Qall + (size_t)src * H + chb + g * 8);

    f32x4 o0 = {0.f, 0.f, 0.f, 0.f}, o1 = {0.f, 0.f, 0.f, 0.f};
    float m = -3.0e38f, s = 0.f;
    for (int kc = 0; kc < nk; kc += 64) {
      // K A-frags straight from global (L2): row = kc+16i+l15, ch 8g..8g+7.
      // Out-of-range rows read row srcL[0]-safe addr 0; masked at p[] below.
      int r0 = kc + l15, r1 = kc + 16 + l15, r2 = kc + 32 + l15, r3 = kc + 48 + l15;
      int s0_ = (r0 < nk) ? srcL[r0] : 0;
      int s1_ = (r1 < nk) ? srcL[r1] : 0;
      int s2_ = (r2 < nk) ? srcL[r2] : 0;
      int s3_ = (r3 < nk) ? srcL[r3] : 0;
      bf16x8 a0 = *(const bf16x8*)(Kall + (size_t)s0_ * H + chb + g * 8);
      bf16x8 a1 = *(const bf16x8*)(Kall + (size_t)s1_ * H + chb + g * 8);
      bf16x8 a2 = *(const bf16x8*)(Kall + (size_t)s2_ * H + chb + g * 8);
      bf16x8 a3 = *(const bf16x8*)(Kall + (size_t)s3_ * H + chb + g * 8);
      f32x4 z = {0.f, 0.f, 0.f, 0.f};
      f32x4 st0 = __builtin_amdgcn_mfma_f32_16x16x32_bf16(a0, bq, z, 0, 0, 0);
      f32x4 st1 = __builtin_amdgcn_mfma_f32_16x16x32_bf16(a1, bq, z, 0, 0, 0);
      f32x4 st2 = __builtin_amdgcn_mfma_f32_16x16x32_bf16(a2, bq, z, 0, 0, 0);
      f32x4 st3 = __builtin_amdgcn_mfma_f32_16x16x32_bf16(a3, bq, z, 0, 0, 0);
      float p[16];
#pragma unroll
      for (int r = 0; r < 4; r++) {
        p[r]      = (kc + 4 * g + r < nk)      ? st0[r] * scale : -1e30f;
        p[4 + r]  = (kc + 16 + 4 * g + r < nk) ? st1[r] * scale : -1e30f;
        p[8 + r]  = (kc + 32 + 4 * g + r < nk) ? st2[r] * scale : -1e30f;
        p[12 + r] = (kc + 48 + 4 * g + r < nk) ? st3[r] * scale : -1e30f;
      }
      float pm = p[0];
#pragma unroll
      for (int r = 1; r < 16; r++) pm = fmaxf(pm, p[r]);
      pm = fmaxf(pm, __shfl_xor(pm, 16));
      pm = fmaxf(pm, __shfl_xor(pm, 32));
      float mn = fmaxf(m, pm);
      float corr = __expf(m - mn);
      float rs = 0.f;
#pragma unroll
      for (int r = 0; r < 16; r++) { p[r] = __expf(p[r] - mn); rs += p[r]; }
      rs += __shfl_xor(rs, 16);
      rs += __shfl_xor(rs, 32);
      s = s * corr + rs;
      m = mn;
      // pack p -> 8 dwords, repack to B-frags via shfl (no LDS)
      unsigned pkw[4][2];
#pragma unroll
      for (int i = 0; i < 4; i++) {
        pkw[i][0] = pack2bf(p[4 * i + 0], p[4 * i + 1]);
        pkw[i][1] = pack2bf(p[4 * i + 2], p[4 * i + 3]);
      }
      union { int i[4]; bf16x8 v; } pb0, pb1;
#pragma unroll
      for (int j = 0; j < 4; j++) {
        int sl = (2 * (g & 1) + (j >> 1)) * 16 + l15;
        int a_ = __shfl((int)pkw[0][j & 1], sl);
        int b_ = __shfl((int)pkw[1][j & 1], sl);
        int c_ = __shfl((int)pkw[2][j & 1], sl);
        int d_ = __shfl((int)pkw[3][j & 1], sl);
        pb0.i[j] = (g < 2) ? a_ : b_;
        pb1.i[j] = (g < 2) ? c_ : d_;
      }
      bf16x8 av00 = *(const bf16x8*)(VTl + l15 * VP + kc + 8 * g);
      bf16x8 av01 = *(const bf16x8*)(VTl + l15 * VP + kc + 32 + 8 * g);
      bf16x8 av10 = *(const bf16x8*)(VTl + (16 + l15) * VP + kc + 8 * g);
      bf16x8 av11 = *(const bf16x8*)(VTl + (16 + l15) * VP + kc + 32 + 8 * g);
#pragma unroll
      for (int r = 0; r < 4; r++) { o0[r] *= corr; o1[r] *= corr; }
      o0 = __builtin_amdgcn_mfma_f32_16x16x32_bf16(av00, pb0.v, o0, 0, 0, 0);
      o0 = __builtin_amdgcn_mfma_f32_16x16x32_bf16(av01, pb1.v, o0, 0, 0, 0);
      o1 = __builtin_amdgcn_mfma_f32_16x16x32_bf16(av10, pb0.v, o1, 0, 0, 0);
      o1 = __builtin_amdgcn_mfma_f32_16x16x32_bf16(av11, pb1.v, o1, 0, 0, 0);
    }
    if (valid) {
      int qi = q0 + slot;
      if (lenq > LQ && slot == LQ - 1) qi = q0 + lenq - 1;
      ushort* outp = CtxB + (size_t)qi * H + chb;
      if (nk > 0) {
        float inv = 1.f / s;
        ushort4 v0, v1;
#pragma unroll
        for (int r = 0; r < 4; r++) { ((ushort*)&v0)[r] = f2bf(o0[r] * inv); ((ushort*)&v1)[r] = f2bf(o1[r] * inv); }
        *(ushort4*)(outp + 4 * g) = v0;
        *(ushort4*)(outp + 16 + 4 * g) = v1;
      } else {
        const float* bv = in_proj_b + 2 * H + chb;
        ushort4 v0, v1;
#pragma unroll
        for (int r = 0; r < 4; r++) { ((ushort*)&v0)[r] = f2bf(bv[4 * g + r]); ((ushort*)&v1)[r] = f2bf(bv[16 + 4 * g + r]); }
        *(ushort4*)(outp + 4 * g) = v0;
        *(ushort4*)(outp + 16 + 4 * g) = v1;
      }
    }
  }
}

// ---------------- K4: out-proj + residual + FFN (16-row blocks) ----------------
__global__ __launch_bounds__(256) void k_out_ffn_mfma(
    const ushort* __restrict__ CtxB, const float* __restrict__ edge_attr,
    const int* __restrict__ sq, const int* __restrict__ eb,
    const ushort* __restrict__ Wb, const float* __restrict__ opb,
    const float* __restrict__ b1, const float* __restrict__ b2,
    float* __restrict__ out) {
  constexpr int IP = 136;  // K=128 pitch
  constexpr int HP = 264;  // K=256 pitch
  __shared__ ushort attB[16 * IP];  // ctx staging, then att bf16
  __shared__ ushort h1L[16 * HP];   // h1 bf16
  const int t = threadIdx.x;
  const int row0 = blockIdx.x * 16;

  for (int idx = t; idx < 16 * 16; idx += 256) {
    int r = idx >> 4, c = idx & 15;
    int i = row0 + r;
    int bb = eb[i];
    int qq0 = sq[bb];
    int lenq = sq[bb + 1] - qq0;
    int src = i;
    if (lenq > LQ && (i - qq0) >= LQ - 1) src = qq0 + lenq - 1;
    *(u16x8*)(attB + r * IP + c * 8) = *(const u16x8*)(CtxB + (size_t)src * H + c * 8);
  }
  __syncthreads();

  const int w = t >> 6, lane = t & 63, g = lane >> 4, l15 = lane & 15;
  const int row = row0 + l15;
  bf16x8 ca[4];
#pragma unroll
  for (int kc = 0; kc < 4; kc++)
    ca[kc] = *(const bf16x8*)(attB + l15 * IP + kc * 32 + g * 8);
  __syncthreads();   // attB free for att writes

  // phase A: att = ctx @ opw^T + opb + edge_attr  (2 ct tiles per wave)
  float att[2][4];
#pragma unroll
  for (int ci = 0; ci < 2; ci++) {
    int ct = w * 2 + ci;
    f32x4 acc = {0.f, 0.f, 0.f, 0.f};
#pragma unroll
    for (int kc = 0; kc < 4; kc++) {
      bf16x8 bw = *(const bf16x8*)(Wb + OPW_OFF + (size_t)(ct * 16 + l15) * H + kc * 32 + g * 8);
      acc = __builtin_amdgcn_mfma_f32_16x16x32_bf16(bw, ca[kc], acc, 0, 0, 0);
    }
    int oc = ct * 16 + 4 * g;
    float4 bo = *(const float4*)(opb + oc);
    float4 ea = *(const float4*)(edge_attr + (size_t)row * H + oc);
    ushort4 v;
    att[ci][0] = acc[0] + bo.x + ea.x; v.x = f2bf(att[ci][0]);
    att[ci][1] = acc[1] + bo.y + ea.y; v.y = f2bf(att[ci][1]);
    att[ci][2] = acc[2] + bo.z + ea.z; v.z = f2bf(att[ci][2]);
    att[ci][3] = acc[3] + bo.w + ea.w; v.w = f2bf(att[ci][3]);
    *(ushort4*)(attB + l15 * IP + oc) = v;
  }
  __syncthreads();

  // phase B: h1 = relu(att @ w1^T + b1)  (4 ct tiles per wave)
  bf16x8 aa[4];
#pragma unroll
  for (int kc = 0; kc < 4; kc++)
    aa[kc] = *(const bf16x8*)(attB + l15 * IP + kc * 32 + g * 8);
#pragma unroll
  for (int ci = 0; ci < 4; ci++) {
    int ct = w * 4 + ci;
    f32x4 acc = {0.f, 0.f, 0.f, 0.f};
#pragma unroll
    for (int kc = 0; kc < 4; kc++) {
      bf16x8 bw = *(const bf16x8*)(Wb + W1_OFF + (size_t)(ct * 16 + l15) * H + kc * 32 + g * 8);
      acc = __builtin_amdgcn_mfma_f32_16x16x32_bf16(bw, aa[kc], acc, 0, 0, 0);
    }
    int oc = ct * 16 + 4 * g;
    float4 bb = *(const float4*)(b1 + oc);
    ushort4 v;
    v.x = f2bf(fmaxf(acc[0] + bb.x, 0.f)); v.y = f2bf(fmaxf(acc[1] + bb.y, 0.f));
    v.z = f2bf(fmaxf(acc[2] + bb.z, 0.f)); v.w = f2bf(fmaxf(acc[3] + bb.w, 0.f));
    *(ushort4*)(h1L + l15 * HP + oc) = v;
  }
  __syncthreads();

  // phase C: out = att + h1 @ w2^T + b2  (same 2 ct tiles as phase A)
  bf16x8 ha[8];
#pragma unroll
  for (int kc = 0; kc < 8; kc++)
    ha[kc] = *(const bf16x8*)(h1L + l15 * HP + kc * 32 + g * 8);
#pragma unroll
  for (int ci = 0; ci < 2; ci++) {
    int ct = w * 2 + ci;
    f32x4 acc = {0.f, 0.f, 0.f, 0.f};
#pragma unroll
    for (int kc = 0; kc < 8; kc++) {
      bf16x8 bw = *(const bf16x8*)(Wb + W2_OFF + (size_t)(ct * 16 + l15) * 2 * H + kc * 32 + g * 8);
      acc = __builtin_amdgcn_mfma_f32_16x16x32_bf16(bw, ha[kc], acc, 0, 0, 0);
    }
    int oc = ct * 16 + 4 * g;
    float4 bb = *(const float4*)(b2 + oc);
    float4 o;
    o.x = att[ci][0] + acc[0] + bb.x;
    o.y = att[ci][1] + acc[1] + bb.y;
    o.z = att[ci][2] + acc[2] + bb.z;
    o.w = att[ci][3] + acc[3] + bb.w;
    *(float4*)(out + (size_t)row * H + oc) = o;
  }
}

extern "C" void kernel_launch(void* const* d_in, const int* in_sizes, int n_in,
                              void* d_out, int out_size, void* d_ws, size_t ws_size,
                              hipStream_t stream) {
  const float* edge_attr = (const float*)d_in[1];
  const int*   iel       = (const int*)d_in[2];
  const int*   ieb       = (const int*)d_in[3];
  const int*   eb        = (const int*)d_in[4];
  const float* in_proj_w = (const float*)d_in[5];
  const float* in_proj_b = (const float*)d_in[6];
  const float* opw       = (const float*)d_in[7];
  const float* opb       = (const float*)d_in[8];
  const float* w1        = (const float*)d_in[9];
  const float* b1        = (const float*)d_in[10];
  const float* w2        = (const float*)d_in[11];
  const float* b2        = (const float*)d_in[12];
  float* out = (float*)d_out;

  char* ws = (char*)d_ws;
  int* sq = (int*)ws;
  int* sk = (int*)(ws + 2048);
  ushort* CtxB = (ushort*)(ws + 4096);            // E*H bf16
  ushort* Wb   = CtxB + (size_t)E * H;            // 131072 bf16 weights
  ushort* Qall = Wb + W_TOTAL;                    // E*H bf16
  ushort* Kall = Qall + (size_t)E * H;            // E*H bf16
  ushort* Vall = Kall + (size_t)E * H;            // E*H bf16

  k_starts_prep<<<dim3(129), dim3(256), 0, stream>>>(eb, ieb, sq, sk, in_proj_w, opw, w1, w2, Wb);
  k_proj_all<<<dim3(E / 32), dim3(256), 0, stream>>>(edge_attr, Wb, in_proj_b, Qall, Kall, Vall);
  k_attn_g<<<dim3(B, NH), dim3(256), 0, stream>>>(Qall, Kall, Vall, iel, in_proj_b, sq, sk, CtxB);
  k_out_ffn_mfma<<<dim3(E / 16), dim3(256), 0, stream>>>(CtxB, edge_attr, sq, eb, Wb, opb, b1, b2, out);
}